// Round 11
// baseline (6822.478 us; speedup 1.0000x reference)
//
#include <hip/hip_runtime.h>
#include <hip/hip_bf16.h>

#define Bv 64
#define Tv 512
#define Iv 1024
#define Hv 1024
#define G4v 4096
#define BH (Bv * Hv)
#define SB 32           // rows per stream (2 independent recurrence streams)
#define NHB 64          // recurrent blocks
#define NXB 128         // producer blocks (2 per 64-col slice, row-split)
#define NBLK (NHB + NXB)
#define DEPTH 8         // xg ring depth (power of 2)
#define FSTR 16         // flag padding: 64B

typedef __attribute__((ext_vector_type(8))) short bf16x8;
typedef __attribute__((ext_vector_type(4))) float f32x4;

#define LOADC(p)    __hip_atomic_load((p), __ATOMIC_RELAXED, __HIP_MEMORY_SCOPE_AGENT)
#define STOREC(p,v) __hip_atomic_store((p), (v), __ATOMIC_RELAXED, __HIP_MEMORY_SCOPE_AGENT)

__device__ __forceinline__ float sigmoid_f(float v) { return 1.f / (1.f + __expf(-v)); }
__device__ __forceinline__ float tanh_f(float v) { return 1.f - 2.f / (__expf(2.f * v) + 1.f); }

// ---------------- prep: weights -> bf16, bias sum, zero h slot0/pingpong + flags ----------------
__global__ void prep(const float* __restrict__ w_ih, const float* __restrict__ w_hh,
                     const float* __restrict__ b_ih, const float* __restrict__ b_hh,
                     __hip_bfloat16* __restrict__ wbih, __hip_bfloat16* __restrict__ wbhh,
                     float* __restrict__ bias, __hip_bfloat16* __restrict__ hbuf,
                     unsigned* __restrict__ hflag, unsigned* __restrict__ xflag) {
  unsigned i = blockIdx.x * 256u + threadIdx.x;   // grid covers exactly 4096*1024
  wbih[i] = __float2bfloat16(w_ih[i]);
  wbhh[i] = __float2bfloat16(w_hh[i]);
  if (i < (unsigned)G4v) bias[i] = b_ih[i] + b_hh[i];
  if (i < 2u * BH) hbuf[i] = __float2bfloat16(0.f);   // ring slot 0 (+1) / pingpong
  if (i < (unsigned)(2 * NHB * FSTR)) hflag[i] = 0u;  // 2 streams x 64 blocks
  if (i < (unsigned)(NXB * FSTR)) xflag[i] = 0u;
}

// ---------------- persistent dataflow LSTM, 2-stream batch-split pipeline ----------------
// blocks 0..63: h-blocks; 64..191: x-producers (R9/R10 protocol per stream).
// The B=64 recurrence = two INDEPENDENT B=32 recurrences (rows 0-31 / 32-63).
// Each step interleaves: [poll s0; GEMM s0; gates s0; publish s0; flag s0]
//                        [poll s1; GEMM s1; gates s1; publish s1; flag s1]
// so stream s's publish->flag-flight->discovery latency (~4us of LLC legs) is
// hidden under the other stream's compute. hflag[s*64+b] per stream; xg slot t
// shared (checked in phase 0; producers require BOTH streams' flags to free).
// Ring mode: reads = normal cached loads from virgin slot t; writes = sc1.
__global__ void __launch_bounds__(256, 1) lstm_main(
    const float* __restrict__ x,
    const __hip_bfloat16* __restrict__ wbih,
    const __hip_bfloat16* __restrict__ wbhh,
    const float* __restrict__ bias,
    __hip_bfloat16* __restrict__ hbuf,   // ring [Tv+1][B][H] or pingpong [2][B][H]
    float* __restrict__ xg,              // [DEPTH][B][4H] f32 ring (sc1)
    float* __restrict__ out,             // B*T*H + B*H + B*H
    unsigned* __restrict__ hflag,        // [2][64] padded
    unsigned* __restrict__ xflag,
    int ring)
{
  extern __shared__ char lds[];
  float* gbuf = (float*)(lds + 131072);  // [32][65] f32, reused per phase

  const int bid  = blockIdx.x;
  const bool is_h = (bid < NHB);
  const int tid  = threadIdx.x;
  const int lane = tid & 63;
  const int wave = tid >> 6;
  const int lrow = lane & 15;
  const int lkg  = lane >> 4;        // 0..3
  const int lk   = lkg * 8;

  const int wg = is_h ? bid : ((bid - NHB) >> 1);   // gate-col slice 0..63
  const int rh = is_h ? 0 : ((bid - NHB) & 1);      // x row-half

  // ---- stage this block's 64x1024 weight slice into LDS (once, swizzled) ----
  {
    const __hip_bfloat16* wsrc = is_h ? wbhh : wbih;
    for (int c = tid; c < 8192; c += 256) {
      int n   = c >> 7;
      int k16 = c & 127;
      int gc  = ((n >> 4) << 10) + (wg << 4) + (n & 15);
      uint4 v = *(const uint4*)(wsrc + ((size_t)gc << 10) + (k16 << 3));
      unsigned byt = (unsigned)((n << 11) + (k16 << 4)) ^ ((unsigned)(n & 7) << 4);
      *(uint4*)(&lds[byt]) = v;
    }
  }
  __syncthreads();

  if (!is_h) {
    // ================= x-producer block (R9-exact; ring-free checks BOTH streams) ==========
    const int j  = bid - NHB;
    const int wr = wave & 1;
    const int wc = wave >> 1;
    const int arow = rh * 32 + wr * 16 + lrow;
    const float* xa = x + (size_t)arow * (Tv * Iv) + lk;

    for (int t = 0; t < Tv; ++t) {
      if (t >= DEPTH) {
        if (wave == 0) {
          const unsigned tgt = (unsigned)(t - DEPTH + 1);
          for (;;) {
            unsigned a = LOADC(&hflag[lane * FSTR]);
            unsigned b = LOADC(&hflag[(64 + lane) * FSTR]);
            if (__all(a >= tgt && b >= tgt)) break;
            __builtin_amdgcn_s_sleep(4);
          }
        }
        __syncthreads();
        asm volatile("" ::: "memory");
      }
      f32x4 acc[2];
      acc[0] = f32x4{0.f,0.f,0.f,0.f}; acc[1] = f32x4{0.f,0.f,0.f,0.f};
      const float* xt = xa + (size_t)t * Iv;
      #pragma unroll 4
      for (int ks = 0; ks < 32; ++ks) {
        int k0 = (ks << 5) + lk;
        float4 f0 = *(const float4*)(xt + (ks << 5));
        float4 f1 = *(const float4*)(xt + (ks << 5) + 4);
        union { __hip_bfloat16 e[8]; bf16x8 v; } u;
        u.e[0] = __float2bfloat16(f0.x); u.e[1] = __float2bfloat16(f0.y);
        u.e[2] = __float2bfloat16(f0.z); u.e[3] = __float2bfloat16(f0.w);
        u.e[4] = __float2bfloat16(f1.x); u.e[5] = __float2bfloat16(f1.y);
        u.e[6] = __float2bfloat16(f1.z); u.e[7] = __float2bfloat16(f1.w);
        bf16x8 b0, b1;
        {
          int n = wc * 32 + lrow;
          unsigned byt = (unsigned)((n << 11) + (k0 << 1)) ^ ((unsigned)(n & 7) << 4);
          b0 = *(const bf16x8*)(&lds[byt]);
          n += 16;
          byt = (unsigned)((n << 11) + (k0 << 1)) ^ ((unsigned)(n & 7) << 4);
          b1 = *(const bf16x8*)(&lds[byt]);
        }
        acc[0] = __builtin_amdgcn_mfma_f32_16x16x32_bf16(u.v, b0, acc[0], 0, 0, 0);
        acc[1] = __builtin_amdgcn_mfma_f32_16x16x32_bf16(u.v, b1, acc[1], 0, 0, 0);
      }
      float* dst = xg + (size_t)(t & (DEPTH - 1)) * (Bv * G4v);
      for (int nf = 0; nf < 2; ++nf) {
        int gc  = (wc * 2 + nf) * 1024 + (wg << 4) + lrow;
        int row = rh * 32 + wr * 16 + (lkg << 2);
        for (int r = 0; r < 4; ++r)
          STOREC(&dst[(size_t)(row + r) * G4v + gc], acc[nf][r]);
      }
      asm volatile("s_waitcnt vmcnt(0)" ::: "memory");
      __syncthreads();
      if (tid == 0) STOREC(&xflag[j * FSTR], (unsigned)(t + 1));
      __syncthreads();
    }
    return;
  }

  // ================= h-recurrent block: two phase-interleaved B=32 streams =================
  const int wm  = wave >> 1;           // row-tile within stream (0..1)
  const int wn  = wave & 1;            // col-half (2 nf each)
  const int er  = tid >> 3;            // elementwise row within stream 0..31
  const int ecl = (tid & 7) << 1;      // elementwise h-col pair base 0..14
  float c_state[2][2] = {{0.f,0.f},{0.f,0.f}};   // [stream][j], static after unroll
  float biasv[8];
  for (int g = 0; g < 4; ++g)
    for (int jj = 0; jj < 2; ++jj)
      biasv[g * 2 + jj] = bias[(g << 10) + (wg << 4) + ecl + jj];

  for (int t = 0; t < Tv; ++t) {
    #pragma unroll
    for (int S = 0; S < 2; ++S) {
      // ---- poll (wave0): stream-S h flags >= t; xg producers >= t+1 (phase 0 only) ----
      if (wave == 0) {
        const unsigned* xf = &xflag[(2 * wg + (lane & 1)) * FSTR];
        for (;;) {
          unsigned hf = LOADC(&hflag[(S * 64 + lane) * FSTR]);
          bool ok = (hf >= (unsigned)t);
          if (S == 0) { unsigned xv = LOADC(xf); ok = ok && (xv >= (unsigned)(t + 1)); }
          if (__all(ok)) break;
          __builtin_amdgcn_s_sleep(1);
        }
      }
      __syncthreads();
      asm volatile("" ::: "memory");
      // ---- xg slice -> registers (4x8B; in flight with the A burst) ----
      float xgv[8];
      {
        const float* xgs = xg + (size_t)(t & (DEPTH - 1)) * (Bv * G4v)
                         + (size_t)(S * SB + er) * G4v + (wg << 4) + ecl;
        #pragma unroll
        for (int g = 0; g < 4; ++g) {
          union { unsigned long long q; float f[2]; } ux;
          ux.q = LOADC((const unsigned long long*)(xgs + (g << 10)));
          xgv[g * 2 + 0] = ux.f[0]; xgv[g * 2 + 1] = ux.f[1];
        }
      }
      // ---- A: 32x16B burst for this stream's 16-row tile ----
      const int ar = S * SB + wm * 16 + lrow;
      f32x4 acc[2];
      acc[0] = f32x4{0.f,0.f,0.f,0.f}; acc[1] = f32x4{0.f,0.f,0.f,0.f};
      if (ring) {
        const char* hrow = (const char*)(hbuf + (size_t)t * BH) + ((size_t)ar << 11) + (lkg << 4);
        bf16x8 aqv[32];
        #pragma unroll
        for (int ks = 0; ks < 32; ++ks)
          aqv[ks] = *(const bf16x8*)(hrow + (ks << 6));
        #pragma unroll
        for (int ks = 0; ks < 32; ++ks) {
          int k0 = (ks << 5) + lk;
          #pragma unroll
          for (int nfl = 0; nfl < 2; ++nfl) {
            int n = (wn * 2 + nfl) * 16 + lrow;
            unsigned byt = (unsigned)((n << 11) + (k0 << 1)) ^ ((unsigned)(n & 7) << 4);
            bf16x8 b = *(const bf16x8*)(&lds[byt]);
            acc[nfl] = __builtin_amdgcn_mfma_f32_16x16x32_bf16(aqv[ks], b, acc[nfl], 0, 0, 0);
          }
        }
      } else {
        const unsigned long long* hq = (const unsigned long long*)
            (hbuf + (size_t)(t & 1) * BH) + (size_t)ar * 256 + lkg * 2;
        bf16x8 aqv[32];
        #pragma unroll
        for (int ks = 0; ks < 32; ++ks) {
          union { unsigned long long q[2]; bf16x8 v; } ua;
          ua.q[0] = LOADC(hq + ks * 8);
          ua.q[1] = LOADC(hq + ks * 8 + 1);
          aqv[ks] = ua.v;
        }
        #pragma unroll
        for (int ks = 0; ks < 32; ++ks) {
          int k0 = (ks << 5) + lk;
          #pragma unroll
          for (int nfl = 0; nfl < 2; ++nfl) {
            int n = (wn * 2 + nfl) * 16 + lrow;
            unsigned byt = (unsigned)((n << 11) + (k0 << 1)) ^ ((unsigned)(n & 7) << 4);
            bf16x8 b = *(const bf16x8*)(&lds[byt]);
            acc[nfl] = __builtin_amdgcn_mfma_f32_16x16x32_bf16(aqv[ks], b, acc[nfl], 0, 0, 0);
          }
        }
      }
      // ---- exchange gates through LDS ([32][65]) ----
      #pragma unroll
      for (int nfl = 0; nfl < 2; ++nfl)
        for (int r = 0; r < 4; ++r)
          gbuf[(wm * 16 + (lkg << 2) + r) * 65 + (wn * 2 + nfl) * 16 + lrow] = acc[nfl][r];
      __syncthreads();
      // ---- gates + elementwise: 2 cells (row er, cols ecl..ecl+1) ----
      float hv[2];
      #pragma unroll
      for (int jj = 0; jj < 2; ++jj) {
        int cc = ecl + jj;
        float g0 = gbuf[er * 65 +      cc] + xgv[0 + jj] + biasv[0 + jj];
        float g1 = gbuf[er * 65 + 16 + cc] + xgv[2 + jj] + biasv[2 + jj];
        float g2 = gbuf[er * 65 + 32 + cc] + xgv[4 + jj] + biasv[4 + jj];
        float g3 = gbuf[er * 65 + 48 + cc] + xgv[6 + jj] + biasv[6 + jj];
        float ig = sigmoid_f(g0);
        float fg = sigmoid_f(g1);
        float gg = tanh_f(g2);
        float og = sigmoid_f(g3);
        float cv = fg * c_state[S][jj] + ig * gg;
        c_state[S][jj] = cv;
        hv[jj] = og * tanh_f(cv);
      }
      // ---- publish h (one 4B sc1 store), drain, flag ----
      {
        __hip_bfloat16* hw = hbuf
            + (ring ? (size_t)(t + 1) * BH : (size_t)((t + 1) & 1) * BH)
            + ((size_t)(S * SB + er) << 10) + (wg << 4) + ecl;
        union { __hip_bfloat16 h[2]; unsigned u; } hu;
        hu.h[0] = __float2bfloat16(hv[0]); hu.h[1] = __float2bfloat16(hv[1]);
        STOREC((unsigned*)hw, hu.u);
      }
      asm volatile("s_waitcnt vmcnt(0)" ::: "memory");
      __syncthreads();
      if (tid == 0) STOREC(&hflag[(S * 64 + wg) * FSTR], (unsigned)(t + 1));
      // ---- out stores after flag: off the critical path ----
      {
        float* ow = out + (size_t)(S * SB + er) * (Tv * Hv) + ((size_t)t << 10) + (wg << 4) + ecl;
        ow[0] = hv[0]; ow[1] = hv[1];
        if (t == Tv - 1) {
          float* hn = out + (size_t)Bv * Tv * Hv + ((size_t)(S * SB + er) << 10) + (wg << 4) + ecl;
          float* cn = hn + (size_t)BH;
          hn[0] = hv[0]; hn[1] = hv[1];
          cn[0] = c_state[S][0]; cn[1] = c_state[S][1];
        }
      }
      __syncthreads();
    }
  }
}

// ---------------- host launch ----------------
extern "C" void kernel_launch(void* const* d_in, const int* in_sizes, int n_in,
                              void* d_out, int out_size, void* d_ws, size_t ws_size,
                              hipStream_t stream) {
  const float* x    = (const float*)d_in[0];
  const float* w_ih = (const float*)d_in[1];
  const float* b_ih = (const float*)d_in[2];
  const float* w_hh = (const float*)d_in[3];
  const float* b_hh = (const float*)d_in[4];
  float* out = (float*)d_out;

  char* ws = (char*)d_ws;
  __hip_bfloat16* wbih = (__hip_bfloat16*)(ws);                        // 8 MB
  __hip_bfloat16* wbhh = (__hip_bfloat16*)(ws + ((size_t)8 << 20));    // 8 MB
  float*          bias = (float*)(ws + ((size_t)16 << 20));            // 16 KB
  float*          xg   = (float*)(ws + ((size_t)18 << 20));            // 8 MB ring
  unsigned*       hflag= (unsigned*)(ws + ((size_t)26 << 20));         // 8 KB (2x64)
  unsigned*       xflag= (unsigned*)(ws + ((size_t)26 << 20) + 8192);  // 8 KB

  const size_t ringBytes = (size_t)(Tv + 1) * BH * 2;
  const size_t needRing  = ((size_t)32 << 20) + ringBytes;
  const int ring = (ws_size >= needRing) ? 1 : 0;
  __hip_bfloat16* hbuf = ring
      ? (__hip_bfloat16*)(ws + ((size_t)32 << 20))
      : (__hip_bfloat16*)(ws + ((size_t)16 << 20) + 65536);

  hipLaunchKernelGGL(prep, dim3(16384), dim3(256), 0, stream,
                     w_ih, w_hh, b_ih, b_hh, wbih, wbhh, bias, hbuf, hflag, xflag);

  const unsigned ldsBytes = 131072u + 32u * 65u * 4u;  // 139392
  hipFuncSetAttribute((const void*)lstm_main,
                      hipFuncAttributeMaxDynamicSharedMemorySize, (int)ldsBytes);

  const float* xA = x;
  const __hip_bfloat16* wbihA = wbih;
  const __hip_bfloat16* wbhhA = wbhh;
  const float* biasA = bias;
  __hip_bfloat16* hbufA = hbuf;
  float* xgA = xg;
  float* outA = out;
  unsigned* hflagA = hflag;
  unsigned* xflagA = xflag;
  int ringA = ring;
  void* args[10] = {(void*)&xA, (void*)&wbihA, (void*)&wbhhA, (void*)&biasA,
                    (void*)&hbufA, (void*)&xgA, (void*)&outA, (void*)&hflagA,
                    (void*)&xflagA, (void*)&ringA};

  // Coop launch can reject silently (R5/R6). Our sync is flag-based only and
  // 139392B LDS forces 1 block/CU -> plain launch co-resides too. Fall back.
  hipError_t lerr = hipLaunchCooperativeKernel((const void*)lstm_main, dim3(NBLK),
                                               dim3(256), args, ldsBytes, stream);
  if (lerr != hipSuccess) {
    (void)hipGetLastError();
    hipLaunchKernelGGL(lstm_main, dim3(NBLK), dim3(256), ldsBytes, stream,
                       xA, wbihA, wbhhA, biasA, hbufA, xgA, outA, hflagA, xflagA, ringA);
  }
}

// Round 12
// 4732.079 us; speedup vs baseline: 1.4418x; 1.4418x over previous
//
#include <hip/hip_runtime.h>
#include <hip/hip_bf16.h>

#define Bv 64
#define Tv 512
#define Iv 1024
#define Hv 1024
#define G4v 4096
#define BH (Bv * Hv)
#define NHB 64          // recurrent blocks
#define NXB 128         // producer blocks (2 per 64-col slice, row-split)
#define NBLK (NHB + NXB)
#define DEPTH 8         // xg ring depth (power of 2)
#define FSTR 16         // flag padding: 64B

typedef __attribute__((ext_vector_type(8))) short bf16x8;
typedef __attribute__((ext_vector_type(4))) float f32x4;

#define LOADC(p)    __hip_atomic_load((p), __ATOMIC_RELAXED, __HIP_MEMORY_SCOPE_AGENT)
#define STOREC(p,v) __hip_atomic_store((p), (v), __ATOMIC_RELAXED, __HIP_MEMORY_SCOPE_AGENT)

__device__ __forceinline__ float sigmoid_f(float v) { return 1.f / (1.f + __expf(-v)); }
__device__ __forceinline__ float tanh_f(float v) { return 1.f - 2.f / (__expf(2.f * v) + 1.f); }

// 2-byte agent-visible (sc1 write-through) store: publish bf16 h cells.
__device__ __forceinline__ void store_short_sc1(void* p, unsigned short v) {
  asm volatile("global_store_short %0, %1, off sc1" :: "v"(p), "v"((unsigned)v) : "memory");
}

// ---------------- prep: weights -> bf16, bias sum, zero h slot0/pingpong + flags ----------------
__global__ void prep(const float* __restrict__ w_ih, const float* __restrict__ w_hh,
                     const float* __restrict__ b_ih, const float* __restrict__ b_hh,
                     __hip_bfloat16* __restrict__ wbih, __hip_bfloat16* __restrict__ wbhh,
                     float* __restrict__ bias, __hip_bfloat16* __restrict__ hbuf,
                     unsigned* __restrict__ hflag, unsigned* __restrict__ xflag) {
  unsigned i = blockIdx.x * 256u + threadIdx.x;   // grid covers exactly 4096*1024
  wbih[i] = __float2bfloat16(w_ih[i]);
  wbhh[i] = __float2bfloat16(w_hh[i]);
  if (i < (unsigned)G4v) bias[i] = b_ih[i] + b_hh[i];
  if (i < 2u * BH) hbuf[i] = __float2bfloat16(0.f);   // ring slots 0-1 / pingpong both
  if (i < (unsigned)(NHB * FSTR)) hflag[i] = 0u;
  if (i < (unsigned)(NXB * FSTR)) xflag[i] = 0u;
}

// ---------------- persistent dataflow LSTM (no grid barrier, no fences) ----------------
// blocks 0..63: h-blocks; blocks 64..191: x-producers (R10 protocol, unchanged).
// R12 h-step: poll -> barrier -> A-burst (cached ring reads) -> xg scalar loads
// (hidden under MFMA) -> MFMA -> elementwise DIRECTLY on C/D fragments (thread
// (wave,lane) owns cells row=wave*16+lkg*4+r, col=wg*16+lrow; nf=0..3 are the
// i/f/g/o fragments for those cells -> NO gbuf LDS exchange, 2 barriers/step).
// Publish = 4x2B sc1 stores; flag after vmcnt(0)+barrier; out after flag.
__global__ void __launch_bounds__(256, 1) lstm_main(
    const float* __restrict__ x,
    const __hip_bfloat16* __restrict__ wbih,
    const __hip_bfloat16* __restrict__ wbhh,
    const float* __restrict__ bias,
    __hip_bfloat16* __restrict__ hbuf,   // ring [Tv+1][B][H] or pingpong [2][B][H]
    float* __restrict__ xg,              // [DEPTH][B][4H] f32 ring (sc1)
    float* __restrict__ out,             // B*T*H + B*H + B*H
    unsigned* __restrict__ hflag,
    unsigned* __restrict__ xflag,
    int ring)
{
  extern __shared__ char lds[];

  const int bid  = blockIdx.x;
  const bool is_h = (bid < NHB);
  const int tid  = threadIdx.x;
  const int lane = tid & 63;
  const int wave = tid >> 6;
  const int lrow = lane & 15;        // A row / B,D col within fragment
  const int lkg  = lane >> 4;        // 0..3
  const int lk   = lkg * 8;          // k offset within 32

  const int wg = is_h ? bid : ((bid - NHB) >> 1);   // gate-col slice 0..63
  const int rh = is_h ? 0 : ((bid - NHB) & 1);      // x row-half

  // ---- stage this block's 64x1024 weight slice into LDS (once, swizzled) ----
  {
    const __hip_bfloat16* wsrc = is_h ? wbhh : wbih;
    for (int c = tid; c < 8192; c += 256) {       // 8192 chunks of 16B = 128KB
      int n   = c >> 7;
      int k16 = c & 127;
      int gc  = ((n >> 4) << 10) + (wg << 4) + (n & 15);
      uint4 v = *(const uint4*)(wsrc + ((size_t)gc << 10) + (k16 << 3));
      unsigned byt = (unsigned)((n << 11) + (k16 << 4)) ^ ((unsigned)(n & 7) << 4);
      *(uint4*)(&lds[byt]) = v;
    }
  }
  __syncthreads();

  if (!is_h) {
    // ================= x-producer block (R10-exact) =================
    const int j  = bid - NHB;
    const int wr = wave & 1;
    const int wc = wave >> 1;
    const int arow = rh * 32 + wr * 16 + lrow;
    const float* xa = x + (size_t)arow * (Tv * Iv) + lk;

    for (int t = 0; t < Tv; ++t) {
      if (t >= DEPTH) {
        if (wave == 0) {
          const unsigned tgt = (unsigned)(t - DEPTH + 1);
          for (;;) {
            unsigned hf = LOADC(&hflag[lane * FSTR]);
            if (__all(hf >= tgt)) break;
            __builtin_amdgcn_s_sleep(4);
          }
        }
        __syncthreads();
        asm volatile("" ::: "memory");
      }
      f32x4 acc[2];
      acc[0] = f32x4{0.f,0.f,0.f,0.f}; acc[1] = f32x4{0.f,0.f,0.f,0.f};
      const float* xt = xa + (size_t)t * Iv;
      #pragma unroll 4
      for (int ks = 0; ks < 32; ++ks) {
        int k0 = (ks << 5) + lk;
        float4 f0 = *(const float4*)(xt + (ks << 5));
        float4 f1 = *(const float4*)(xt + (ks << 5) + 4);
        union { __hip_bfloat16 e[8]; bf16x8 v; } u;
        u.e[0] = __float2bfloat16(f0.x); u.e[1] = __float2bfloat16(f0.y);
        u.e[2] = __float2bfloat16(f0.z); u.e[3] = __float2bfloat16(f0.w);
        u.e[4] = __float2bfloat16(f1.x); u.e[5] = __float2bfloat16(f1.y);
        u.e[6] = __float2bfloat16(f1.z); u.e[7] = __float2bfloat16(f1.w);
        bf16x8 b0, b1;
        {
          int n = wc * 32 + lrow;
          unsigned byt = (unsigned)((n << 11) + (k0 << 1)) ^ ((unsigned)(n & 7) << 4);
          b0 = *(const bf16x8*)(&lds[byt]);
          n += 16;
          byt = (unsigned)((n << 11) + (k0 << 1)) ^ ((unsigned)(n & 7) << 4);
          b1 = *(const bf16x8*)(&lds[byt]);
        }
        acc[0] = __builtin_amdgcn_mfma_f32_16x16x32_bf16(u.v, b0, acc[0], 0, 0, 0);
        acc[1] = __builtin_amdgcn_mfma_f32_16x16x32_bf16(u.v, b1, acc[1], 0, 0, 0);
      }
      float* dst = xg + (size_t)(t & (DEPTH - 1)) * (Bv * G4v);
      for (int nf = 0; nf < 2; ++nf) {
        int gc  = (wc * 2 + nf) * 1024 + (wg << 4) + lrow;
        int row = rh * 32 + wr * 16 + (lkg << 2);
        for (int r = 0; r < 4; ++r)
          STOREC(&dst[(size_t)(row + r) * G4v + gc], acc[nf][r]);
      }
      asm volatile("s_waitcnt vmcnt(0)" ::: "memory");
      __syncthreads();
      if (tid == 0) STOREC(&xflag[j * FSTR], (unsigned)(t + 1));
      __syncthreads();
    }
    return;
  }

  // ================= h-recurrent block =================
  // Thread (wave,lane) owns output cells: rows wave*16+lkg*4+{0..3}, col wg*16+lrow.
  const int orow0 = wave * 16 + (lkg << 2);  // first owned batch row
  const int ocol  = (wg << 4) + lrow;        // owned h column (global)
  float c_state[4] = {0.f, 0.f, 0.f, 0.f};
  float biasv[4];
  #pragma unroll
  for (int g = 0; g < 4; ++g) biasv[g] = bias[(g << 10) + ocol];

  const int ar = wave * 16 + lrow;     // A row this lane loads (16 rows per wave)

  for (int t = 0; t < Tv; ++t) {
    // ---- poll (wave 0 only): all h-blocks done t-1; my 2 xg producers done t ----
    if (wave == 0) {
      const unsigned ht = (unsigned)t, xtg = (unsigned)(t + 1);
      const unsigned* xf = &xflag[(2 * wg + (lane & 1)) * FSTR];
      for (;;) {
        unsigned hf = LOADC(&hflag[lane * FSTR]);
        unsigned xv = LOADC(xf);
        if (__all(hf >= ht && xv >= xtg)) break;
        __builtin_amdgcn_s_sleep(1);
      }
    }
    __syncthreads();
    asm volatile("" ::: "memory");
    // ---- A burst FIRST (MFMA waits only on these) ----
    f32x4 acc[4];
    for (int nf = 0; nf < 4; ++nf) acc[nf] = f32x4{0.f,0.f,0.f,0.f};
    bf16x8 aqv[32];
    const unsigned long long* hq = nullptr;
    if (ring) {
      const char* hrow = (const char*)(hbuf + (size_t)t * BH) + ((size_t)ar << 11) + (lkg << 4);
      #pragma unroll
      for (int ks = 0; ks < 32; ++ks)
        aqv[ks] = *(const bf16x8*)(hrow + (ks << 6));
    } else {
      hq = (const unsigned long long*)(hbuf + (size_t)(t & 1) * BH) + (size_t)ar * 256 + lkg * 2;
      #pragma unroll
      for (int ks = 0; ks < 32; ++ks) {
        union { unsigned long long q[2]; bf16x8 v; } ua;
        ua.q[0] = LOADC(hq + ks * 8);
        ua.q[1] = LOADC(hq + ks * 8 + 1);
        aqv[ks] = ua.v;
      }
    }
    // ---- xg scalar loads for OWN cells (16x4B sc1) — hidden under MFMA ----
    float xgv[16];   // [g][r]
    {
      const float* xgs = xg + (size_t)(t & (DEPTH - 1)) * (Bv * G4v);
      #pragma unroll
      for (int g = 0; g < 4; ++g)
        #pragma unroll
        for (int r = 0; r < 4; ++r)
          xgv[g * 4 + r] = LOADC(xgs + (size_t)(orow0 + r) * G4v + (g << 10) + ocol);
    }
    // ---- MFMA: nf = gate index (i,f,g,o fragments of col ocol) ----
    #pragma unroll
    for (int ks = 0; ks < 32; ++ks) {
      int k0 = (ks << 5) + lk;
      #pragma unroll
      for (int nf = 0; nf < 4; ++nf) {
        int n = nf * 16 + lrow;
        unsigned byt = (unsigned)((n << 11) + (k0 << 1)) ^ ((unsigned)(n & 7) << 4);
        bf16x8 b = *(const bf16x8*)(&lds[byt]);
        acc[nf] = __builtin_amdgcn_mfma_f32_16x16x32_bf16(aqv[ks], b, acc[nf], 0, 0, 0);
      }
    }
    // ---- elementwise directly on fragments: cells (orow0+r, ocol) ----
    float hv[4];
    #pragma unroll
    for (int r = 0; r < 4; ++r) {
      float g0 = acc[0][r] + xgv[0 + r]  + biasv[0];
      float g1 = acc[1][r] + xgv[4 + r]  + biasv[1];
      float g2 = acc[2][r] + xgv[8 + r]  + biasv[2];
      float g3 = acc[3][r] + xgv[12 + r] + biasv[3];
      float ig = sigmoid_f(g0);
      float fg = sigmoid_f(g1);
      float gg = tanh_f(g2);
      float og = sigmoid_f(g3);
      float cv = fg * c_state[r] + ig * gg;
      c_state[r] = cv;
      hv[r] = og * tanh_f(cv);
    }
    // ---- publish h: 4 x 2B sc1 write-through stores (rows orow0+r, col ocol) ----
    {
      __hip_bfloat16* hs = hbuf
          + (ring ? (size_t)(t + 1) * BH : (size_t)((t + 1) & 1) * BH) + ocol;
      #pragma unroll
      for (int r = 0; r < 4; ++r) {
        __hip_bfloat16 hb = __float2bfloat16(hv[r]);
        store_short_sc1(hs + ((size_t)(orow0 + r) << 10), *(unsigned short*)&hb);
      }
    }
    asm volatile("s_waitcnt vmcnt(0)" ::: "memory");
    __syncthreads();                    // all waves' h stores at LLC
    if (tid == 0) STOREC(&hflag[wg * FSTR], (unsigned)(t + 1));
    // ---- out stores AFTER flag (no trailing barrier; next poll+barrier orders) ----
    #pragma unroll
    for (int r = 0; r < 4; ++r) {
      float* ow = out + (size_t)(orow0 + r) * (Tv * Hv) + ((size_t)t << 10) + ocol;
      __builtin_nontemporal_store(hv[r], ow);
    }
    if (t == Tv - 1) {
      #pragma unroll
      for (int r = 0; r < 4; ++r) {
        float* hn = out + (size_t)Bv * Tv * Hv + ((size_t)(orow0 + r) << 10) + ocol;
        __builtin_nontemporal_store(hv[r], hn);
        __builtin_nontemporal_store(c_state[r], hn + BH);
      }
    }
  }
}

// ---------------- host launch ----------------
extern "C" void kernel_launch(void* const* d_in, const int* in_sizes, int n_in,
                              void* d_out, int out_size, void* d_ws, size_t ws_size,
                              hipStream_t stream) {
  const float* x    = (const float*)d_in[0];
  const float* w_ih = (const float*)d_in[1];
  const float* b_ih = (const float*)d_in[2];
  const float* w_hh = (const float*)d_in[3];
  const float* b_hh = (const float*)d_in[4];
  float* out = (float*)d_out;

  char* ws = (char*)d_ws;
  __hip_bfloat16* wbih = (__hip_bfloat16*)(ws);                        // 8 MB
  __hip_bfloat16* wbhh = (__hip_bfloat16*)(ws + ((size_t)8 << 20));    // 8 MB
  float*          bias = (float*)(ws + ((size_t)16 << 20));            // 16 KB
  float*          xg   = (float*)(ws + ((size_t)18 << 20));            // 8 MB ring
  unsigned*       hflag= (unsigned*)(ws + ((size_t)26 << 20));         // 4 KB
  unsigned*       xflag= (unsigned*)(ws + ((size_t)26 << 20) + 8192);  // 8 KB

  const size_t ringBytes = (size_t)(Tv + 1) * BH * 2;
  const size_t needRing  = ((size_t)32 << 20) + ringBytes;
  const int ring = (ws_size >= needRing) ? 1 : 0;
  __hip_bfloat16* hbuf = ring
      ? (__hip_bfloat16*)(ws + ((size_t)32 << 20))
      : (__hip_bfloat16*)(ws + ((size_t)16 << 20) + 65536);

  hipLaunchKernelGGL(prep, dim3(16384), dim3(256), 0, stream,
                     w_ih, w_hh, b_ih, b_hh, wbih, wbhh, bias, hbuf, hflag, xflag);

  const unsigned ldsBytes = 131072u;   // weights only (gbuf exchange removed)
  hipFuncSetAttribute((const void*)lstm_main,
                      hipFuncAttributeMaxDynamicSharedMemorySize, (int)ldsBytes);

  const float* xA = x;
  const __hip_bfloat16* wbihA = wbih;
  const __hip_bfloat16* wbhhA = wbhh;
  const float* biasA = bias;
  __hip_bfloat16* hbufA = hbuf;
  float* xgA = xg;
  float* outA = out;
  unsigned* hflagA = hflag;
  unsigned* xflagA = xflag;
  int ringA = ring;
  void* args[10] = {(void*)&xA, (void*)&wbihA, (void*)&wbhhA, (void*)&biasA,
                    (void*)&hbufA, (void*)&xgA, (void*)&outA, (void*)&hflagA,
                    (void*)&xflagA, (void*)&ringA};

  // Coop launch can reject silently (R5/R6). Our sync is flag-based only and
  // 131072B LDS still forces 1 block/CU -> plain launch co-resides too.
  hipError_t lerr = hipLaunchCooperativeKernel((const void*)lstm_main, dim3(NBLK),
                                               dim3(256), args, ldsBytes, stream);
  if (lerr != hipSuccess) {
    (void)hipGetLastError();
    hipLaunchKernelGGL(lstm_main, dim3(NBLK), dim3(256), ldsBytes, stream,
                       xA, wbihA, wbhhA, biasA, hbufA, xgA, outA, hflagA, xflagA, ringA);
  }
}